// Round 9
// baseline (233.289 us; speedup 1.0000x reference)
//
#include <hip/hip_runtime.h>

#define HW 16384   // 128*128
#define NC 256     // C
#define NB 16      // B

typedef float floatx4 __attribute__((ext_vector_type(4)));

__device__ __forceinline__ float sum4(floatx4 v) { return (v.x + v.y) + (v.z + v.w); }
__device__ __forceinline__ floatx4 ntload(const floatx4* p) {
    return __builtin_nontemporal_load(p);
}

// ---------------------------------------------------------------------------
// CONFIG B (steady-state cache design, validated R8: 265 -> 216.6us):
//   * ALL large tensor reads non-temporal (no L3 allocation, no dirty-victim
//     writebacks).
//   * out stores regular caching stores -> L3 converges to the out buffer
//     (same addresses every replay), permanently dirty-resident: stores are
//     write HITS, out ~never flows to HBM.
//   Structural HBM traffic: 536 (pool) + 536 (apply) MB. Any attempt to
//   cache inputs trades 1:1 against out writebacks (wash) — this is minimal.
// R9: apply gets deep ILP (8 nt loads in flight) — R8's apply was the R2
// VGPR=12 body, ~2 loads in flight, latency-bound at ~4.5 TB/s on what are
// now guaranteed all-miss streams.
// ---------------------------------------------------------------------------

// ---------------------------------------------------------------------------
// Kernel 1: global average pool. 4096 blocks x 256 threads. Block bc reads
// plane bc of BOTH tensors with nt float4 loads, 16 loads in flight,
// independent partial accumulators, wave reduce, LDS combine. (frozen)
// ---------------------------------------------------------------------------
__global__ __launch_bounds__(256, 4) void pool_kernel(const float* __restrict__ fft,
                                                      const float* __restrict__ multi,
                                                      float* __restrict__ pooled) {
    int bc = blockIdx.x;             // 0..4095 = b*256 + c
    int tid = threadIdx.x;
    int lane = tid & 63, wid = tid >> 6;
    const floatx4* fbase = (const floatx4*)fft + ((size_t)bc << 12) + tid;
    const floatx4* mbase = (const floatx4*)multi + ((size_t)bc << 12) + tid;

    float fs0 = 0.f, fs1 = 0.f, fs2 = 0.f, fs3 = 0.f;
    float fs4 = 0.f, fs5 = 0.f, fs6 = 0.f, fs7 = 0.f;
    float ms0 = 0.f, ms1 = 0.f, ms2 = 0.f, ms3 = 0.f;
    float ms4 = 0.f, ms5 = 0.f, ms6 = 0.f, ms7 = 0.f;

#pragma unroll
    for (int chunk = 0; chunk < 2; ++chunk) {
        const floatx4* pf = fbase + chunk * 2048;
        const floatx4* pm = mbase + chunk * 2048;
        floatx4 f0 = ntload(pf + 0),    f1 = ntload(pf + 256);
        floatx4 f2 = ntload(pf + 512),  f3 = ntload(pf + 768);
        floatx4 f4 = ntload(pf + 1024), f5 = ntload(pf + 1280);
        floatx4 f6 = ntload(pf + 1536), f7 = ntload(pf + 1792);
        floatx4 m0 = ntload(pm + 0),    m1 = ntload(pm + 256);
        floatx4 m2 = ntload(pm + 512),  m3 = ntload(pm + 768);
        floatx4 m4 = ntload(pm + 1024), m5 = ntload(pm + 1280);
        floatx4 m6 = ntload(pm + 1536), m7 = ntload(pm + 1792);
        fs0 += sum4(f0); fs1 += sum4(f1); fs2 += sum4(f2); fs3 += sum4(f3);
        fs4 += sum4(f4); fs5 += sum4(f5); fs6 += sum4(f6); fs7 += sum4(f7);
        ms0 += sum4(m0); ms1 += sum4(m1); ms2 += sum4(m2); ms3 += sum4(m3);
        ms4 += sum4(m4); ms5 += sum4(m5); ms6 += sum4(m6); ms7 += sum4(m7);
    }
    float fsum = ((fs0 + fs1) + (fs2 + fs3)) + ((fs4 + fs5) + (fs6 + fs7));
    float msum = ((ms0 + ms1) + (ms2 + ms3)) + ((ms4 + ms5) + (ms6 + ms7));

#pragma unroll
    for (int off = 32; off > 0; off >>= 1) {
        fsum += __shfl_xor(fsum, off, 64);
        msum += __shfl_xor(msum, off, 64);
    }

    __shared__ float ws[4][2];
    if (lane == 0) { ws[wid][0] = fsum; ws[wid][1] = msum; }
    __syncthreads();
    if (tid < 2) {
        float s = (ws[0][tid] + ws[1][tid]) + (ws[2][tid] + ws[3][tid]);
        int b = bc >> 8, c = bc & 255;
        pooled[b * 512 + tid * 256 + c] = s * (1.0f / HW);
    }
}

// ---------------------------------------------------------------------------
// Kernel 2a: h[b][r] = relu(sum_c pooled[b][c] * w1[r][c]),  w1: [64][512]
// ---------------------------------------------------------------------------
__global__ __launch_bounds__(256) void mlp1_kernel(const float* __restrict__ pooled,
                                                   const float* __restrict__ w1,
                                                   float* __restrict__ h) {
    int wid = (blockIdx.x << 2) | (threadIdx.x >> 6);   // 0..1023
    int lane = threadIdx.x & 63;
    int b = wid >> 6, r = wid & 63;
    const float4* w = (const float4*)(w1 + (size_t)r * 512) + (lane << 1);
    const float4* p = (const float4*)(pooled + b * 512) + (lane << 1);
    float4 wa = w[0], wb = w[1];
    float4 pa = p[0], pb = p[1];
    float s = wa.x * pa.x + wa.y * pa.y + wa.z * pa.z + wa.w * pa.w
            + wb.x * pb.x + wb.y * pb.y + wb.z * pb.z + wb.w * pb.w;
#pragma unroll
    for (int off = 32; off > 0; off >>= 1) s += __shfl_xor(s, off, 64);
    if (lane == 0) h[wid] = fmaxf(s, 0.f);
}

// ---------------------------------------------------------------------------
// Kernel 2b: attn[b][c] = sigmoid(sum_r h[b][r] * w2[c][r]),  w2: [512][64]
// ---------------------------------------------------------------------------
__global__ __launch_bounds__(256) void mlp2_kernel(const float* __restrict__ h,
                                                   const float* __restrict__ w2,
                                                   float* __restrict__ attn) {
    int wid = (blockIdx.x << 2) | (threadIdx.x >> 6);   // 0..8191
    int lane = threadIdx.x & 63;
    int b = wid >> 9, c = wid & 511;
    float s = h[(b << 6) | lane] * w2[((size_t)c << 6) | lane];
#pragma unroll
    for (int off = 32; off > 0; off >>= 1) s += __shfl_xor(s, off, 64);
    if (lane == 0) attn[(b << 9) | c] = 1.0f / (1.0f + __expf(-s));
}

// ---------------------------------------------------------------------------
// Kernel 3: out = attn[b][c]*fft + attn[b][256+c]*multi.
// EXACTLY 4096 blocks x 256 threads: thread i0 (< 2^20) handles float4s
// i0 + k*2^20, k=0..15; plane of element k is (b=k, c=i0>>12) -> attn loads
// are wave-uniform broadcasts. 8 nt loads in flight per batch (all-miss
// streams need deep MLP-independent ILP; safe now that Config B removed the
// dirty-victim writeback entanglement that poisoned R5/R7's deep-ILP test).
// Loads NT (no L3 allocation), stores CACHING (write-hit the resident out).
// ---------------------------------------------------------------------------
__global__ __launch_bounds__(256) void apply_kernel(const float* __restrict__ fft,
                                                    const float* __restrict__ multi,
                                                    const float* __restrict__ attn,
                                                    float* __restrict__ out) {
    const floatx4* f4 = (const floatx4*)fft;
    const floatx4* m4 = (const floatx4*)multi;
    floatx4* o4 = (floatx4*)out;
    const size_t stride = (size_t)1 << 20;             // 4096*256 threads
    size_t i0 = (size_t)blockIdx.x * 256 + threadIdx.x;
    int c = (int)(i0 >> 12);                           // wave-uniform channel

#pragma unroll
    for (int outer = 0; outer < 4; ++outer) {
        size_t ia = i0 + (size_t)(4 * outer + 0) * stride;
        size_t ib = i0 + (size_t)(4 * outer + 1) * stride;
        size_t ic = i0 + (size_t)(4 * outer + 2) * stride;
        size_t id = i0 + (size_t)(4 * outer + 3) * stride;
        // 8 independent nt loads issued back-to-back
        floatx4 fa = ntload(f4 + ia), fb = ntload(f4 + ib);
        floatx4 fc = ntload(f4 + ic), fd = ntload(f4 + id);
        floatx4 ma = ntload(m4 + ia), mb = ntload(m4 + ib);
        floatx4 mc = ntload(m4 + ic), md = ntload(m4 + id);
        // broadcast attn weights (b = 4*outer+j), tiny cached table
        int ba = 4 * outer;
        float fwa = attn[(ba + 0) * 512 + c],       fwb = attn[(ba + 1) * 512 + c];
        float fwc = attn[(ba + 2) * 512 + c],       fwd = attn[(ba + 3) * 512 + c];
        float mwa = attn[(ba + 0) * 512 + 256 + c], mwb = attn[(ba + 1) * 512 + 256 + c];
        float mwc = attn[(ba + 2) * 512 + 256 + c], mwd = attn[(ba + 3) * 512 + 256 + c];
        floatx4 oa, ob, oc, od;
        oa.x = fmaf(fwa, fa.x, mwa * ma.x); oa.y = fmaf(fwa, fa.y, mwa * ma.y);
        oa.z = fmaf(fwa, fa.z, mwa * ma.z); oa.w = fmaf(fwa, fa.w, mwa * ma.w);
        ob.x = fmaf(fwb, fb.x, mwb * mb.x); ob.y = fmaf(fwb, fb.y, mwb * mb.y);
        ob.z = fmaf(fwb, fb.z, mwb * mb.z); ob.w = fmaf(fwb, fb.w, mwb * mb.w);
        oc.x = fmaf(fwc, fc.x, mwc * mc.x); oc.y = fmaf(fwc, fc.y, mwc * mc.y);
        oc.z = fmaf(fwc, fc.z, mwc * mc.z); oc.w = fmaf(fwc, fc.w, mwc * mc.w);
        od.x = fmaf(fwd, fd.x, mwd * md.x); od.y = fmaf(fwd, fd.y, mwd * md.y);
        od.z = fmaf(fwd, fd.z, mwd * md.z); od.w = fmaf(fwd, fd.w, mwd * md.w);
        o4[ia] = oa;
        o4[ib] = ob;
        o4[ic] = oc;
        o4[id] = od;
    }
}

extern "C" void kernel_launch(void* const* d_in, const int* in_sizes, int n_in,
                              void* d_out, int out_size, void* d_ws, size_t ws_size,
                              hipStream_t stream) {
    const float* fft   = (const float*)d_in[0];
    const float* multi = (const float*)d_in[1];
    const float* w1    = (const float*)d_in[2];   // [64][512]
    const float* w2    = (const float*)d_in[3];   // [512][64]
    float* out = (float*)d_out;

    float* pooled = (float*)d_ws;                 // [16][512]
    float* h      = pooled + NB * 512;            // [16][64]
    float* attn   = h + NB * 64;                  // [16][512]

    pool_kernel<<<4096, 256, 0, stream>>>(fft, multi, pooled);
    mlp1_kernel<<<256, 256, 0, stream>>>(pooled, w1, h);
    mlp2_kernel<<<2048, 256, 0, stream>>>(h, w2, attn);
    apply_kernel<<<4096, 256, 0, stream>>>(fft, multi, attn, out);
}

// Round 10
// 215.994 us; speedup vs baseline: 1.0801x; 1.0801x over previous
//
#include <hip/hip_runtime.h>

#define HW 16384   // 128*128
#define NC 256     // C
#define NB 16      // B

typedef float floatx4 __attribute__((ext_vector_type(4)));

__device__ __forceinline__ float sum4(floatx4 v) { return (v.x + v.y) + (v.z + v.w); }
__device__ __forceinline__ floatx4 ntload(const floatx4* p) {
    return __builtin_nontemporal_load(p);
}

// ---------------------------------------------------------------------------
// Traffic ledger (measured through R9): pool fetches ~536 MB, apply fetches
// ~268 (50% L3) + writes 268. R9 falsified "out stays dirty-resident"
// (WRITE=268 MB every replay). Lesson bank: deep ILP helps ONLY with
// contiguous per-block streams (pool ~11 TB/s effective); direct-index
// 16MB-spaced streams lost 3x (R6/R7/R9). R10: apply adopts pool's shape.
// ---------------------------------------------------------------------------

// ---------------------------------------------------------------------------
// Kernel 1: global average pool. 4096 blocks x 256 threads. Block bc reads
// plane bc of BOTH tensors with nt float4 loads, 16 loads in flight,
// independent partial accumulators, wave reduce, LDS combine. (frozen)
// ---------------------------------------------------------------------------
__global__ __launch_bounds__(256, 4) void pool_kernel(const float* __restrict__ fft,
                                                      const float* __restrict__ multi,
                                                      float* __restrict__ pooled) {
    int bc = blockIdx.x;             // 0..4095 = b*256 + c
    int tid = threadIdx.x;
    int lane = tid & 63, wid = tid >> 6;
    const floatx4* fbase = (const floatx4*)fft + ((size_t)bc << 12) + tid;
    const floatx4* mbase = (const floatx4*)multi + ((size_t)bc << 12) + tid;

    float fs0 = 0.f, fs1 = 0.f, fs2 = 0.f, fs3 = 0.f;
    float fs4 = 0.f, fs5 = 0.f, fs6 = 0.f, fs7 = 0.f;
    float ms0 = 0.f, ms1 = 0.f, ms2 = 0.f, ms3 = 0.f;
    float ms4 = 0.f, ms5 = 0.f, ms6 = 0.f, ms7 = 0.f;

#pragma unroll
    for (int chunk = 0; chunk < 2; ++chunk) {
        const floatx4* pf = fbase + chunk * 2048;
        const floatx4* pm = mbase + chunk * 2048;
        floatx4 f0 = ntload(pf + 0),    f1 = ntload(pf + 256);
        floatx4 f2 = ntload(pf + 512),  f3 = ntload(pf + 768);
        floatx4 f4 = ntload(pf + 1024), f5 = ntload(pf + 1280);
        floatx4 f6 = ntload(pf + 1536), f7 = ntload(pf + 1792);
        floatx4 m0 = ntload(pm + 0),    m1 = ntload(pm + 256);
        floatx4 m2 = ntload(pm + 512),  m3 = ntload(pm + 768);
        floatx4 m4 = ntload(pm + 1024), m5 = ntload(pm + 1280);
        floatx4 m6 = ntload(pm + 1536), m7 = ntload(pm + 1792);
        fs0 += sum4(f0); fs1 += sum4(f1); fs2 += sum4(f2); fs3 += sum4(f3);
        fs4 += sum4(f4); fs5 += sum4(f5); fs6 += sum4(f6); fs7 += sum4(f7);
        ms0 += sum4(m0); ms1 += sum4(m1); ms2 += sum4(m2); ms3 += sum4(m3);
        ms4 += sum4(m4); ms5 += sum4(m5); ms6 += sum4(m6); ms7 += sum4(m7);
    }
    float fsum = ((fs0 + fs1) + (fs2 + fs3)) + ((fs4 + fs5) + (fs6 + fs7));
    float msum = ((ms0 + ms1) + (ms2 + ms3)) + ((ms4 + ms5) + (ms6 + ms7));

#pragma unroll
    for (int off = 32; off > 0; off >>= 1) {
        fsum += __shfl_xor(fsum, off, 64);
        msum += __shfl_xor(msum, off, 64);
    }

    __shared__ float ws[4][2];
    if (lane == 0) { ws[wid][0] = fsum; ws[wid][1] = msum; }
    __syncthreads();
    if (tid < 2) {
        float s = (ws[0][tid] + ws[1][tid]) + (ws[2][tid] + ws[3][tid]);
        int b = bc >> 8, c = bc & 255;
        pooled[b * 512 + tid * 256 + c] = s * (1.0f / HW);
    }
}

// ---------------------------------------------------------------------------
// Kernel 2a: h[b][r] = relu(sum_c pooled[b][c] * w1[r][c]),  w1: [64][512]
// ---------------------------------------------------------------------------
__global__ __launch_bounds__(256) void mlp1_kernel(const float* __restrict__ pooled,
                                                   const float* __restrict__ w1,
                                                   float* __restrict__ h) {
    int wid = (blockIdx.x << 2) | (threadIdx.x >> 6);   // 0..1023
    int lane = threadIdx.x & 63;
    int b = wid >> 6, r = wid & 63;
    const float4* w = (const float4*)(w1 + (size_t)r * 512) + (lane << 1);
    const float4* p = (const float4*)(pooled + b * 512) + (lane << 1);
    float4 wa = w[0], wb = w[1];
    float4 pa = p[0], pb = p[1];
    float s = wa.x * pa.x + wa.y * pa.y + wa.z * pa.z + wa.w * pa.w
            + wb.x * pb.x + wb.y * pb.y + wb.z * pb.z + wb.w * pb.w;
#pragma unroll
    for (int off = 32; off > 0; off >>= 1) s += __shfl_xor(s, off, 64);
    if (lane == 0) h[wid] = fmaxf(s, 0.f);
}

// ---------------------------------------------------------------------------
// Kernel 2b: attn[b][c] = sigmoid(sum_r h[b][r] * w2[c][r]),  w2: [512][64]
// ---------------------------------------------------------------------------
__global__ __launch_bounds__(256) void mlp2_kernel(const float* __restrict__ h,
                                                   const float* __restrict__ w2,
                                                   float* __restrict__ attn) {
    int wid = (blockIdx.x << 2) | (threadIdx.x >> 6);   // 0..8191
    int lane = threadIdx.x & 63;
    int b = wid >> 9, c = wid & 511;
    float s = h[(b << 6) | lane] * w2[((size_t)c << 6) | lane];
#pragma unroll
    for (int off = 32; off > 0; off >>= 1) s += __shfl_xor(s, off, 64);
    if (lane == 0) attn[(b << 9) | c] = 1.0f / (1.0f + __expf(-s));
}

// ---------------------------------------------------------------------------
// Kernel 3: out = fw*fft + mw*multi — POOL-SHAPED. 2048 blocks x 256 threads.
// Block g owns planes {2g, 2g+1} CONTIGUOUSLY (2 x 64 KB windows). Per plane:
// attn weights are wave-uniform (scalar loads), then 4 batches of
// {4 nt f-loads + 4 nt m-loads in flight, FMA, 4 caching stores} marching
// a 16 KB sliding window. Deep ILP + per-block contiguity (the combination
// pool proved at ~11 TB/s effective read) — unlike the thrice-failed
// 16MB-strided direct-index shape. Loads nt; stores caching (R6: nt stores
// cost +65us).
// ---------------------------------------------------------------------------
__global__ __launch_bounds__(256) void apply_kernel(const float* __restrict__ fft,
                                                    const float* __restrict__ multi,
                                                    const float* __restrict__ attn,
                                                    float* __restrict__ out) {
    int g = blockIdx.x;              // 0..2047
    int tid = threadIdx.x;

#pragma unroll
    for (int pl = 0; pl < 2; ++pl) {
        int plane = (g << 1) | pl;   // b*256 + c
        int b = plane >> 8, c = plane & 255;
        float fw = attn[b * 512 + c];            // wave-uniform -> s_load
        float mw = attn[b * 512 + 256 + c];
        const floatx4* pf = (const floatx4*)fft + ((size_t)plane << 12) + tid;
        const floatx4* pm = (const floatx4*)multi + ((size_t)plane << 12) + tid;
        floatx4* po = (floatx4*)out + ((size_t)plane << 12) + tid;

#pragma unroll
        for (int it = 0; it < 4; ++it) {
            const floatx4* qf = pf + it * 1024;
            const floatx4* qm = pm + it * 1024;
            floatx4* qo = po + it * 1024;
            // 8 independent nt loads in flight, all within a 16 KB window
            floatx4 f0 = ntload(qf + 0),   f1 = ntload(qf + 256);
            floatx4 f2 = ntload(qf + 512), f3 = ntload(qf + 768);
            floatx4 m0 = ntload(qm + 0),   m1 = ntload(qm + 256);
            floatx4 m2 = ntload(qm + 512), m3 = ntload(qm + 768);
            floatx4 o0, o1, o2, o3;
            o0.x = fmaf(fw, f0.x, mw * m0.x); o0.y = fmaf(fw, f0.y, mw * m0.y);
            o0.z = fmaf(fw, f0.z, mw * m0.z); o0.w = fmaf(fw, f0.w, mw * m0.w);
            o1.x = fmaf(fw, f1.x, mw * m1.x); o1.y = fmaf(fw, f1.y, mw * m1.y);
            o1.z = fmaf(fw, f1.z, mw * m1.z); o1.w = fmaf(fw, f1.w, mw * m1.w);
            o2.x = fmaf(fw, f2.x, mw * m2.x); o2.y = fmaf(fw, f2.y, mw * m2.y);
            o2.z = fmaf(fw, f2.z, mw * m2.z); o2.w = fmaf(fw, f2.w, mw * m2.w);
            o3.x = fmaf(fw, f3.x, mw * m3.x); o3.y = fmaf(fw, f3.y, mw * m3.y);
            o3.z = fmaf(fw, f3.z, mw * m3.z); o3.w = fmaf(fw, f3.w, mw * m3.w);
            qo[0]   = o0;
            qo[256] = o1;
            qo[512] = o2;
            qo[768] = o3;
        }
    }
}

extern "C" void kernel_launch(void* const* d_in, const int* in_sizes, int n_in,
                              void* d_out, int out_size, void* d_ws, size_t ws_size,
                              hipStream_t stream) {
    const float* fft   = (const float*)d_in[0];
    const float* multi = (const float*)d_in[1];
    const float* w1    = (const float*)d_in[2];   // [64][512]
    const float* w2    = (const float*)d_in[3];   // [512][64]
    float* out = (float*)d_out;

    float* pooled = (float*)d_ws;                 // [16][512]
    float* h      = pooled + NB * 512;            // [16][64]
    float* attn   = h + NB * 64;                  // [16][512]

    pool_kernel<<<4096, 256, 0, stream>>>(fft, multi, pooled);
    mlp1_kernel<<<256, 256, 0, stream>>>(pooled, w1, h);
    mlp2_kernel<<<2048, 256, 0, stream>>>(h, w2, attn);
    apply_kernel<<<2048, 256, 0, stream>>>(fft, multi, attn, out);
}